// Round 23
// baseline (573.092 us; speedup 1.0000x reference)
//
#include <hip/hip_runtime.h>
#include <hip/hip_bf16.h>

typedef __attribute__((ext_vector_type(8))) short bf16x8;
typedef __attribute__((ext_vector_type(4))) float f32x4;

#define B_    4
#define L_    2048
#define D_    256
#define H_    8
#define DH_   32
#define DFF_  1024
#define BL_   (B_*L_)          // 8192
#define RES_ELEMS (BL_*D_)     // 2097152
#define EFP   2056             // padded Ef row stride (bf16 elems)

__device__ __forceinline__ float bf2f(ushort u){
  union { unsigned int i; float f; } v; v.i = ((unsigned int)u)<<16; return v.f;
}
__device__ __forceinline__ ushort f2bf(float f){
  union { float f; unsigned int i; } v; v.f = f;
  unsigned int u = v.i;
  u += 0x7fffu + ((u>>16)&1u);   // round-to-nearest-even
  return (ushort)(u>>16);
}
__device__ __forceinline__ unsigned cvt_pk_bf16(float a, float b){
  unsigned r;
  asm("v_cvt_pk_bf16_f32 %0, %1, %2" : "=v"(r) : "v"(a), "v"(b));
  return r;
}
__device__ __forceinline__ float fast_exp2(float x){
  float r;
  asm("v_exp_f32 %0, %1" : "=v"(r) : "v"(x));
  return r;
}

// ---------------- prep v2 (UNCHANGED r22-pass) ----------------
__global__ void prep_kernel(const float* x, const float* Wq, const float* Wk, const float* Wv,
                            const float* Wo, const float* W1, const float* W2,
                            ushort* xb, ushort* wqt, ushort* wkt, ushort* wvt, ushort* wot,
                            ushort* w1b, ushort* w2b){
  int i = blockIdx.x*256 + threadIdx.x;
  const int NX4 = (BL_*D_) >> 2;       // 524288
  const int NW = D_*D_;
  const int NF = DFF_*D_;
  if (i < NX4){
    float4 v = *(const float4*)(x + (size_t)i*4);
    uint2 u = {cvt_pk_bf16(v.x, v.y), cvt_pk_bf16(v.z, v.w)};
    *(uint2*)(xb + (size_t)i*4) = u;
    return;
  }
  i -= NX4;
  if (i < NW) { int c = i>>8, k = i&255; wqt[i] = f2bf(Wq[k*D_+c]); return; }
  i -= NW;
  if (i < NW) { int c = i>>8, k = i&255; wkt[i] = f2bf(Wk[k*D_+c]); return; }
  i -= NW;
  if (i < NW) { int c = i>>8, k = i&255; wvt[i] = f2bf(Wv[k*D_+c]); return; }
  i -= NW;
  if (i < NW) { int c = i>>8, k = i&255; wot[i] = f2bf(Wo[k*D_+c]); return; }
  i -= NW;
  if (i < NF) { w1b[i] = f2bf(W1[i]); return; }
  i -= NF;
  if (i < NF) { w2b[i] = f2bf(W2[i]); return; }
}

// ---------------- qkv GEMM v2 (UNCHANGED r22-pass) ----------------
__global__ __launch_bounds__(256) void qkv_gemm(const ushort* __restrict__ xb,
                         const ushort* __restrict__ wqt, const ushort* __restrict__ wkt,
                         const ushort* __restrict__ wvt,
                         ushort* __restrict__ qb, ushort* __restrict__ kb, ushort* __restrict__ vtb){
  int lane = threadIdx.x & 63, w = threadIdx.x >> 6;
  int rt = blockIdx.x, cg = blockIdx.y, mat = blockIdx.z;
  const ushort* Bt = (mat==0) ? wqt : (mat==1) ? wkt : wvt;
  int wr = w >> 1, wc = w & 1;
  int row0 = rt*64 + wr*32 + (lane & 15);
  int col0 = cg*64 + wc*32 + (lane & 15);
  int kseg = lane >> 4;
  f32x4 acc00 = {0,0,0,0}, acc01 = {0,0,0,0}, acc10 = {0,0,0,0}, acc11 = {0,0,0,0};
  const ushort* a0p = xb + (size_t)row0*D_ + kseg*8;
  const ushort* a1p = a0p + (size_t)16*D_;
  const ushort* b0p = Bt + (size_t)col0*D_ + kseg*8;
  const ushort* b1p = b0p + (size_t)16*D_;
  #pragma unroll
  for (int kt = 0; kt < 8; ++kt){
    bf16x8 a0 = *(const bf16x8*)(a0p + kt*32);
    bf16x8 a1 = *(const bf16x8*)(a1p + kt*32);
    bf16x8 b0 = *(const bf16x8*)(b0p + kt*32);
    bf16x8 b1 = *(const bf16x8*)(b1p + kt*32);
    acc00 = __builtin_amdgcn_mfma_f32_16x16x32_bf16(a0, b0, acc00, 0, 0, 0);
    acc01 = __builtin_amdgcn_mfma_f32_16x16x32_bf16(a0, b1, acc01, 0, 0, 0);
    acc10 = __builtin_amdgcn_mfma_f32_16x16x32_bf16(a1, b0, acc10, 0, 0, 0);
    acc11 = __builtin_amdgcn_mfma_f32_16x16x32_bf16(a1, b1, acc11, 0, 0, 0);
  }
  const float SCL2E = 0.17677669529663687f * 1.4426950408889634f;
  float scl = (mat==0) ? SCL2E : 1.0f;
  #pragma unroll
  for (int i = 0; i < 2; ++i){
    #pragma unroll
    for (int j = 0; j < 2; ++j){
      f32x4 acc = (i==0) ? (j==0?acc00:acc01) : (j==0?acc10:acc11);
      int rbase = rt*64 + wr*32 + i*16 + (lane>>4)*4;
      int col   = cg*64 + wc*32 + j*16 + (lane & 15);
      if (mat < 2){
        ushort* out = (mat==0) ? qb : kb;
        #pragma unroll
        for (int r = 0; r < 4; ++r) out[(size_t)(rbase+r)*D_ + col] = f2bf(acc[r]*scl);
      } else {
        int b = rbase >> 11, l = rbase & (L_-1);
        int h = col >> 5, d = col & 31;
        ushort* p = vtb + ((size_t)((b*H_ + h)*DH_ + d))*L_ + l;
        #pragma unroll
        for (int r = 0; r < 4; ++r) p[r] = f2bf(acc[r]);
      }
    }
  }
}

// ---------------- attention v10 + setprio (UNCHANGED r22-pass) ----------------
__global__ __launch_bounds__(256) void attn_kernel(const ushort* __restrict__ qb,
                          const ushort* __restrict__ kb, const ushort* __restrict__ vtb,
                          float* __restrict__ attn_out, ushort* __restrict__ ob){
  __shared__ ushort Ef[16][EFP];        // packed bf16 E (64.3 KB)
  __shared__ float part[4*16*32];
  __shared__ float red[4][16];
  __shared__ float rrowInv[16];
  int tid = threadIdx.x, lane = tid & 63, w = tid >> 6;
  int bh = blockIdx.x, rt = blockIdx.y;    // bh fastest -> XCD = bh%8
  int b = bh >> 3, h = bh & 7;
  int l0 = rt*16;
  int ql = lane & 15, g = lane >> 4;

  bf16x8 qfrag = *(const bf16x8*)(qb + (size_t)(b*L_ + l0 + ql)*D_ + h*DH_ + g*8);
  const ushort* kbase = kb + (size_t)(b)*L_*D_ + h*DH_ + g*8;

  float ssum = 0.f;
  f32x4 acc0 = {0.f,0.f,0.f,0.f}, acc1 = {0.f,0.f,0.f,0.f};
  const ushort* v0p = vtb + ((size_t)(bh*DH_) + ql)*L_;
  const ushort* v1p = vtb + ((size_t)(bh*DH_) + 16 + ql)*L_;

  __builtin_amdgcn_s_setprio(1);
  for (int jj = 0; jj < 4; ++jj){
    bf16x8 kf[8];
    bf16x8 vf0[4], vf1[4];
    #pragma unroll
    for (int p = 0; p < 8; ++p){
      int ct = w*32 + jj*8 + p;
      kf[p] = *(const bf16x8*)(kbase + (size_t)(ct*16 + ql)*D_);
    }
    #pragma unroll
    for (int q = 0; q < 4; ++q){
      int kt = w*16 + jj*4 + q;
      vf0[q] = *(const bf16x8*)(v0p + kt*32 + g*8);
      vf1[q] = *(const bf16x8*)(v1p + kt*32 + g*8);
    }
    #pragma unroll
    for (int p = 0; p < 8; ++p){
      int ct = w*32 + jj*8 + p;
      f32x4 acc = {0.f,0.f,0.f,0.f};
      acc = __builtin_amdgcn_mfma_f32_16x16x32_bf16(kf[p], qfrag, acc, 0, 0, 0);
      float e0 = fast_exp2(acc[0]);
      float e1 = fast_exp2(acc[1]);
      float e2 = fast_exp2(acc[2]);
      float e3 = fast_exp2(acc[3]);
      ssum += (e0 + e1) + (e2 + e3);
      uint2 u = {cvt_pk_bf16(e0, e1), cvt_pk_bf16(e2, e3)};
      *(uint2*)(&Ef[ql][ct*16 + g*4]) = u;
    }
    #pragma unroll
    for (int q = 0; q < 4; ++q){
      int kt = w*16 + jj*4 + q;
      bf16x8 pf = *(const bf16x8*)(&Ef[ql][kt*32 + g*8]);
      acc0 = __builtin_amdgcn_mfma_f32_16x16x32_bf16(pf, vf0[q], acc0, 0, 0, 0);
      acc1 = __builtin_amdgcn_mfma_f32_16x16x32_bf16(pf, vf1[q], acc1, 0, 0, 0);
    }
  }
  __builtin_amdgcn_s_setprio(0);

  ssum += __shfl_xor(ssum, 16);
  ssum += __shfl_xor(ssum, 32);
  if (lane < 16) red[w][ql] = ssum;
  {
    int rb = g*4;
    #pragma unroll
    for (int r = 0; r < 4; ++r){
      part[(w*16 + rb + r)*32 + ql]      = acc0[r];
      part[(w*16 + rb + r)*32 + 16 + ql] = acc1[r];
    }
  }
  __syncthreads();
  if (tid < 16)
    rrowInv[tid] = 1.f / (red[0][tid] + red[1][tid] + red[2][tid] + red[3][tid]);
  __syncthreads();

  float* obase = attn_out + ((size_t)bh*L_ + l0)*L_;
  #pragma unroll
  for (int r = 0; r < 16; ++r){
    float rv = rrowInv[r];
    float* orow = obase + (size_t)r*L_;
    #pragma unroll
    for (int rd = 0; rd < 2; ++rd){
      int off = rd*1024 + tid*4;
      uint2 u = *(const uint2*)(&Ef[r][off]);
      float4 st;
      st.x = __uint_as_float(u.x << 16) * rv;
      st.y = __uint_as_float(u.x & 0xffff0000u) * rv;
      st.z = __uint_as_float(u.y << 16) * rv;
      st.w = __uint_as_float(u.y & 0xffff0000u) * rv;
      *(float4*)(orow + off) = st;
    }
  }

  for (int idx = tid; idx < 512; idx += 256){
    int row = idx >> 5, d = idx & 31;
    float sum = (part[(0*16+row)*32 + d] + part[(1*16+row)*32 + d]
               + part[(2*16+row)*32 + d] + part[(3*16+row)*32 + d]) * rrowInv[row];
    ob[(size_t)(b*L_ + l0 + row)*D_ + h*DH_ + d] = f2bf(sum);
  }
}

// ---------------- generic GEMM v2 (UNCHANGED r22-pass) ----------------
template<int EPI>
__global__ __launch_bounds__(256) void gemm_bt(const ushort* __restrict__ A, const ushort* __restrict__ Bt,
                        int M, int N, int K,
                        const float* __restrict__ add, float* __restrict__ outf,
                        ushort* __restrict__ outh){
  int lane = threadIdx.x & 63, w = threadIdx.x >> 6;
  int wr = w >> 1, wc = w & 1;
  int row0 = blockIdx.x*64 + wr*32 + (lane & 15);
  int col0 = blockIdx.y*64 + wc*32 + (lane & 15);
  int kseg = lane >> 4;
  f32x4 acc00 = {0,0,0,0}, acc01 = {0,0,0,0}, acc10 = {0,0,0,0}, acc11 = {0,0,0,0};
  const ushort* a0p = A + (size_t)row0*K + kseg*8;
  const ushort* a1p = a0p + (size_t)16*K;
  const ushort* b0p = Bt + (size_t)col0*K + kseg*8;
  const ushort* b1p = b0p + (size_t)16*K;
  int nk = K >> 5;
  #pragma unroll 4
  for (int kt = 0; kt < nk; ++kt){
    bf16x8 a0 = *(const bf16x8*)(a0p + kt*32);
    bf16x8 a1 = *(const bf16x8*)(a1p + kt*32);
    bf16x8 b0 = *(const bf16x8*)(b0p + kt*32);
    bf16x8 b1 = *(const bf16x8*)(b1p + kt*32);
    acc00 = __builtin_amdgcn_mfma_f32_16x16x32_bf16(a0, b0, acc00, 0, 0, 0);
    acc01 = __builtin_amdgcn_mfma_f32_16x16x32_bf16(a0, b1, acc01, 0, 0, 0);
    acc10 = __builtin_amdgcn_mfma_f32_16x16x32_bf16(a1, b0, acc10, 0, 0, 0);
    acc11 = __builtin_amdgcn_mfma_f32_16x16x32_bf16(a1, b1, acc11, 0, 0, 0);
  }
  #pragma unroll
  for (int i = 0; i < 2; ++i){
    #pragma unroll
    for (int j = 0; j < 2; ++j){
      f32x4 acc = (i==0) ? (j==0?acc00:acc01) : (j==0?acc10:acc11);
      int rbase = blockIdx.x*64 + wr*32 + i*16 + (lane>>4)*4;
      int col   = blockIdx.y*64 + wc*32 + j*16 + (lane & 15);
      #pragma unroll
      for (int r = 0; r < 4; ++r){
        size_t o = (size_t)(rbase + r)*N + col;
        float v = acc[r];
        if (EPI == 1) outh[o] = f2bf(fmaxf(v, 0.f));
        else if (EPI == 2) outf[o] = add[o] + v;
      }
    }
  }
}

// ---------------- decomp v2 (UNCHANGED r22-pass) ----------------
template<int WHICH>
__global__ __launch_bounds__(256) void decomp_kernel(const float* __restrict__ in,
                                                     float* __restrict__ outf,
                                                     ushort* __restrict__ outh){
  int t = threadIdx.x;
  int gl = blockIdx.x*4 + (t >> 6);
  int c4 = (t & 63)*4;
  int b = gl >> 11, l = gl & (L_-1);
  const float* base = in + ((size_t)b*L_)*D_ + c4;
  float4 s = {0.f,0.f,0.f,0.f};
  float4 ctr;
  #pragma unroll
  for (int o = -3; o <= 3; ++o){
    int ll = (l + o + L_) & (L_-1);
    float4 v = *(const float4*)(base + (size_t)ll*D_);
    if (o == 0) ctr = v;
    s.x += v.x; s.y += v.y; s.z += v.z; s.w += v.w;
  }
  const float r7 = 1.f/7.f;
  float4 vv;
  vv.x = ctr.x - s.x*r7;
  vv.y = ctr.y - s.y*r7;
  vv.z = ctr.z - s.z*r7;
  vv.w = ctr.w - s.w*r7;
  size_t o0 = (size_t)gl*D_ + c4;
  if (WHICH == 0){
    *(float4*)(outf + o0) = vv;
    uint2 u = {cvt_pk_bf16(vv.x, vv.y), cvt_pk_bf16(vv.z, vv.w)};
    *(uint2*)(outh + o0) = u;
  } else {
    *(float4*)(outf + o0) = vv;
  }
}

__global__ void ws_diag_kernel(float* res0, float encoded){
  if (threadIdx.x == 0 && blockIdx.x == 0) res0[0] = encoded;
}

extern "C" void kernel_launch(void* const* d_in, const int* in_sizes, int n_in,
                              void* d_out, int out_size, void* d_ws, size_t ws_size,
                              hipStream_t stream) {
  const float* x  = (const float*)d_in[0];
  const float* Wq = (const float*)d_in[1];
  const float* Wk = (const float*)d_in[2];
  const float* Wv = (const float*)d_in[3];
  const float* Wo = (const float*)d_in[4];
  const float* W1 = (const float*)d_in[5];
  const float* W2 = (const float*)d_in[6];

  float* out      = (float*)d_out;
  float* res_out  = out;
  float* attn_out = out + RES_ELEMS;

  const size_t MiB = 1024ull*1024ull;
  const size_t NEEDED = 36*MiB + (MiB + MiB/2);

  if (ws_size < NEEDED){
    float enc = 1048576.0f + 1024.0f * (float)(ws_size / MiB);
    ws_diag_kernel<<<1, 64, 0, stream>>>(res_out, enc);
    return;
  }

  char* ws = (char*)d_ws;
  ushort* xb  = (ushort*)(ws + 0);
  ushort* ob  = (ushort*)(ws + 0);
  ushort* xdb = (ushort*)(ws + 0);
  ushort* qb  = (ushort*)(ws + 4*MiB);
  ushort* kb  = (ushort*)(ws + 8*MiB);
  float*  x1f = (float*) (ws + 4*MiB);
  float*  sf  = (float*) (ws + 4*MiB);
  ushort* vtb = (ushort*)(ws + 12*MiB);
  float*  xdf = (float*) (ws + 12*MiB);
  ushort* hb  = (ushort*)(ws + 20*MiB);
  ushort* wqt = (ushort*)(ws + 36*MiB);
  ushort* wkt = (ushort*)(ws + 36*MiB + 128*1024);
  ushort* wvt = (ushort*)(ws + 36*MiB + 256*1024);
  ushort* wot = (ushort*)(ws + 36*MiB + 384*1024);
  ushort* w1b = (ushort*)(ws + 36*MiB + 512*1024);
  ushort* w2b = (ushort*)(ws + 36*MiB + 1024*1024);

  // 1. prep
  {
    int total = (BL_*D_)/4 + 4*D_*D_ + 2*DFF_*D_;
    prep_kernel<<<(total+255)/256, 256, 0, stream>>>(x, Wq, Wk, Wv, Wo, W1, W2,
                                                     xb, wqt, wkt, wvt, wot, w1b, w2b);
  }
  // 2. QKV projections — x4 TAIL PROBE (idempotent)
  for (int rep = 0; rep < 4; ++rep)
    qkv_gemm<<<dim3(BL_/64, D_/64, 3), 256, 0, stream>>>(xb, wqt, wkt, wvt, qb, kb, vtb);
  // 3. attention v10 + setprio
  attn_kernel<<<dim3(B_*H_, L_/16), 256, 0, stream>>>(qb, kb, vtb, attn_out, ob);
  // 4. O projection + residual — x4 TAIL PROBE
  for (int rep = 0; rep < 4; ++rep)
    gemm_bt<2><<<dim3(BL_/64, D_/64), 256, 0, stream>>>(ob, wot, BL_, D_, D_, x, x1f, nullptr);
  // 5. decomp1
  decomp_kernel<0><<<BL_/4, 256, 0, stream>>>(x1f, xdf, xdb);
  // 6. FFN1 — x4 TAIL PROBE
  for (int rep = 0; rep < 4; ++rep)
    gemm_bt<1><<<dim3(BL_/64, DFF_/64), 256, 0, stream>>>(xdb, w1b, BL_, DFF_, D_, nullptr, nullptr, hb);
  // 7. FFN2 + residual — x4 TAIL PROBE
  for (int rep = 0; rep < 4; ++rep)
    gemm_bt<2><<<dim3(BL_/64, D_/64), 256, 0, stream>>>(hb, w2b, BL_, D_, DFF_, xdf, sf, nullptr);
  // 8. decomp2 -> fp32 res
  decomp_kernel<1><<<BL_/4, 256, 0, stream>>>(sf, res_out, nullptr);
}

// Round 24
// 262.124 us; speedup vs baseline: 2.1863x; 2.1863x over previous
//
#include <hip/hip_runtime.h>
#include <hip/hip_bf16.h>

typedef __attribute__((ext_vector_type(8))) short bf16x8;
typedef __attribute__((ext_vector_type(4))) float f32x4;

#define B_    4
#define L_    2048
#define D_    256
#define H_    8
#define DH_   32
#define DFF_  1024
#define BL_   (B_*L_)          // 8192
#define RES_ELEMS (BL_*D_)     // 2097152
#define EFP   2056             // padded Ef row stride (bf16 elems)

__device__ __forceinline__ float bf2f(ushort u){
  union { unsigned int i; float f; } v; v.i = ((unsigned int)u)<<16; return v.f;
}
__device__ __forceinline__ ushort f2bf(float f){
  union { float f; unsigned int i; } v; v.f = f;
  unsigned int u = v.i;
  u += 0x7fffu + ((u>>16)&1u);   // round-to-nearest-even
  return (ushort)(u>>16);
}
__device__ __forceinline__ unsigned cvt_pk_bf16(float a, float b){
  unsigned r;
  asm("v_cvt_pk_bf16_f32 %0, %1, %2" : "=v"(r) : "v"(a), "v"(b));
  return r;
}
__device__ __forceinline__ float fast_exp2(float x){
  float r;
  asm("v_exp_f32 %0, %1" : "=v"(r) : "v"(x));
  return r;
}

// ---------------- prep v2 (UNCHANGED r22-pass) ----------------
__global__ void prep_kernel(const float* x, const float* Wq, const float* Wk, const float* Wv,
                            const float* Wo, const float* W1, const float* W2,
                            ushort* xb, ushort* wqt, ushort* wkt, ushort* wvt, ushort* wot,
                            ushort* w1b, ushort* w2b){
  int i = blockIdx.x*256 + threadIdx.x;
  const int NX4 = (BL_*D_) >> 2;       // 524288
  const int NW = D_*D_;
  const int NF = DFF_*D_;
  if (i < NX4){
    float4 v = *(const float4*)(x + (size_t)i*4);
    uint2 u = {cvt_pk_bf16(v.x, v.y), cvt_pk_bf16(v.z, v.w)};
    *(uint2*)(xb + (size_t)i*4) = u;
    return;
  }
  i -= NX4;
  if (i < NW) { int c = i>>8, k = i&255; wqt[i] = f2bf(Wq[k*D_+c]); return; }
  i -= NW;
  if (i < NW) { int c = i>>8, k = i&255; wkt[i] = f2bf(Wk[k*D_+c]); return; }
  i -= NW;
  if (i < NW) { int c = i>>8, k = i&255; wvt[i] = f2bf(Wv[k*D_+c]); return; }
  i -= NW;
  if (i < NW) { int c = i>>8, k = i&255; wot[i] = f2bf(Wo[k*D_+c]); return; }
  i -= NW;
  if (i < NF) { w1b[i] = f2bf(W1[i]); return; }
  i -= NF;
  if (i < NF) { w2b[i] = f2bf(W2[i]); return; }
}

// ---------------- qkv GEMM v3: 64x128 block, 32x64/wave (2 A x 4 B = 8 MFMA / 6 loads) ----------------
// grid (BL_/64, D_/128, 3), 4 waves: wr = w&1 (row half), wc = w>>1 (col half).
__global__ __launch_bounds__(256) void qkv_gemm(const ushort* __restrict__ xb,
                         const ushort* __restrict__ wqt, const ushort* __restrict__ wkt,
                         const ushort* __restrict__ wvt,
                         ushort* __restrict__ qb, ushort* __restrict__ kb, ushort* __restrict__ vtb){
  int lane = threadIdx.x & 63, w = threadIdx.x >> 6;
  int rt = blockIdx.x, cg = blockIdx.y, mat = blockIdx.z;
  const ushort* Bt = (mat==0) ? wqt : (mat==1) ? wkt : wvt;
  int wr = w & 1, wc = w >> 1;
  int row0 = rt*64 + wr*32 + (lane & 15);
  int colb = cg*128 + wc*64;
  int kseg = lane >> 4;
  f32x4 acc[2][4] = {};
  const ushort* a0p = xb + (size_t)row0*D_ + kseg*8;
  const ushort* a1p = a0p + (size_t)16*D_;
  const ushort* bp0 = Bt + (size_t)(colb + (lane & 15))*D_ + kseg*8;
  #pragma unroll
  for (int kt = 0; kt < 8; ++kt){
    bf16x8 a0 = *(const bf16x8*)(a0p + kt*32);
    bf16x8 a1 = *(const bf16x8*)(a1p + kt*32);
    #pragma unroll
    for (int j = 0; j < 4; ++j){
      bf16x8 bj = *(const bf16x8*)(bp0 + (size_t)(j*16)*D_ + kt*32);
      acc[0][j] = __builtin_amdgcn_mfma_f32_16x16x32_bf16(a0, bj, acc[0][j], 0, 0, 0);
      acc[1][j] = __builtin_amdgcn_mfma_f32_16x16x32_bf16(a1, bj, acc[1][j], 0, 0, 0);
    }
  }
  const float SCL2E = 0.17677669529663687f * 1.4426950408889634f;
  float scl = (mat==0) ? SCL2E : 1.0f;
  #pragma unroll
  for (int i = 0; i < 2; ++i){
    #pragma unroll
    for (int j = 0; j < 4; ++j){
      int rbase = rt*64 + wr*32 + i*16 + (lane>>4)*4;
      int col   = colb + j*16 + (lane & 15);
      if (mat < 2){
        ushort* out = (mat==0) ? qb : kb;
        #pragma unroll
        for (int r = 0; r < 4; ++r) out[(size_t)(rbase+r)*D_ + col] = f2bf(acc[i][j][r]*scl);
      } else {
        int b = rbase >> 11, l = rbase & (L_-1);
        int h = col >> 5, d = col & 31;
        ushort* p = vtb + ((size_t)((b*H_ + h)*DH_ + d))*L_ + l;
        #pragma unroll
        for (int r = 0; r < 4; ++r) p[r] = f2bf(acc[i][j][r]);
      }
    }
  }
}

// ---------------- attention v10 + setprio (UNCHANGED r22-pass) ----------------
__global__ __launch_bounds__(256) void attn_kernel(const ushort* __restrict__ qb,
                          const ushort* __restrict__ kb, const ushort* __restrict__ vtb,
                          float* __restrict__ attn_out, ushort* __restrict__ ob){
  __shared__ ushort Ef[16][EFP];        // packed bf16 E (64.3 KB)
  __shared__ float part[4*16*32];
  __shared__ float red[4][16];
  __shared__ float rrowInv[16];
  int tid = threadIdx.x, lane = tid & 63, w = tid >> 6;
  int bh = blockIdx.x, rt = blockIdx.y;    // bh fastest -> XCD = bh%8
  int b = bh >> 3, h = bh & 7;
  int l0 = rt*16;
  int ql = lane & 15, g = lane >> 4;

  bf16x8 qfrag = *(const bf16x8*)(qb + (size_t)(b*L_ + l0 + ql)*D_ + h*DH_ + g*8);
  const ushort* kbase = kb + (size_t)(b)*L_*D_ + h*DH_ + g*8;

  float ssum = 0.f;
  f32x4 acc0 = {0.f,0.f,0.f,0.f}, acc1 = {0.f,0.f,0.f,0.f};
  const ushort* v0p = vtb + ((size_t)(bh*DH_) + ql)*L_;
  const ushort* v1p = vtb + ((size_t)(bh*DH_) + 16 + ql)*L_;

  __builtin_amdgcn_s_setprio(1);
  for (int jj = 0; jj < 4; ++jj){
    bf16x8 kf[8];
    bf16x8 vf0[4], vf1[4];
    #pragma unroll
    for (int p = 0; p < 8; ++p){
      int ct = w*32 + jj*8 + p;
      kf[p] = *(const bf16x8*)(kbase + (size_t)(ct*16 + ql)*D_);
    }
    #pragma unroll
    for (int q = 0; q < 4; ++q){
      int kt = w*16 + jj*4 + q;
      vf0[q] = *(const bf16x8*)(v0p + kt*32 + g*8);
      vf1[q] = *(const bf16x8*)(v1p + kt*32 + g*8);
    }
    #pragma unroll
    for (int p = 0; p < 8; ++p){
      int ct = w*32 + jj*8 + p;
      f32x4 acc = {0.f,0.f,0.f,0.f};
      acc = __builtin_amdgcn_mfma_f32_16x16x32_bf16(kf[p], qfrag, acc, 0, 0, 0);
      float e0 = fast_exp2(acc[0]);
      float e1 = fast_exp2(acc[1]);
      float e2 = fast_exp2(acc[2]);
      float e3 = fast_exp2(acc[3]);
      ssum += (e0 + e1) + (e2 + e3);
      uint2 u = {cvt_pk_bf16(e0, e1), cvt_pk_bf16(e2, e3)};
      *(uint2*)(&Ef[ql][ct*16 + g*4]) = u;
    }
    #pragma unroll
    for (int q = 0; q < 4; ++q){
      int kt = w*16 + jj*4 + q;
      bf16x8 pf = *(const bf16x8*)(&Ef[ql][kt*32 + g*8]);
      acc0 = __builtin_amdgcn_mfma_f32_16x16x32_bf16(pf, vf0[q], acc0, 0, 0, 0);
      acc1 = __builtin_amdgcn_mfma_f32_16x16x32_bf16(pf, vf1[q], acc1, 0, 0, 0);
    }
  }
  __builtin_amdgcn_s_setprio(0);

  ssum += __shfl_xor(ssum, 16);
  ssum += __shfl_xor(ssum, 32);
  if (lane < 16) red[w][ql] = ssum;
  {
    int rb = g*4;
    #pragma unroll
    for (int r = 0; r < 4; ++r){
      part[(w*16 + rb + r)*32 + ql]      = acc0[r];
      part[(w*16 + rb + r)*32 + 16 + ql] = acc1[r];
    }
  }
  __syncthreads();
  if (tid < 16)
    rrowInv[tid] = 1.f / (red[0][tid] + red[1][tid] + red[2][tid] + red[3][tid]);
  __syncthreads();

  float* obase = attn_out + ((size_t)bh*L_ + l0)*L_;
  #pragma unroll
  for (int r = 0; r < 16; ++r){
    float rv = rrowInv[r];
    float* orow = obase + (size_t)r*L_;
    #pragma unroll
    for (int rd = 0; rd < 2; ++rd){
      int off = rd*1024 + tid*4;
      uint2 u = *(const uint2*)(&Ef[r][off]);
      float4 st;
      st.x = __uint_as_float(u.x << 16) * rv;
      st.y = __uint_as_float(u.x & 0xffff0000u) * rv;
      st.z = __uint_as_float(u.y << 16) * rv;
      st.w = __uint_as_float(u.y & 0xffff0000u) * rv;
      *(float4*)(orow + off) = st;
    }
  }

  for (int idx = tid; idx < 512; idx += 256){
    int row = idx >> 5, d = idx & 31;
    float sum = (part[(0*16+row)*32 + d] + part[(1*16+row)*32 + d]
               + part[(2*16+row)*32 + d] + part[(3*16+row)*32 + d]) * rrowInv[row];
    ob[(size_t)(b*L_ + l0 + row)*D_ + h*DH_ + d] = f2bf(sum);
  }
}

// ---------------- generic GEMM v3: 64x128 block, 32x64/wave ----------------
// EPI 1: out_bf16 = relu(acc);  EPI 2: out_f32 = add[o] + acc.  grid (M/64, N/128).
template<int EPI>
__global__ __launch_bounds__(256) void gemm_bt(const ushort* __restrict__ A, const ushort* __restrict__ Bt,
                        int M, int N, int K,
                        const float* __restrict__ add, float* __restrict__ outf,
                        ushort* __restrict__ outh){
  int lane = threadIdx.x & 63, w = threadIdx.x >> 6;
  int wr = w & 1, wc = w >> 1;
  int row0 = blockIdx.x*64 + wr*32 + (lane & 15);
  int colb = blockIdx.y*128 + wc*64;
  int kseg = lane >> 4;
  f32x4 acc[2][4] = {};
  const ushort* a0p = A + (size_t)row0*K + kseg*8;
  const ushort* a1p = a0p + (size_t)16*K;
  const ushort* bp0 = Bt + (size_t)(colb + (lane & 15))*K + kseg*8;
  int nk = K >> 5;
  #pragma unroll 4
  for (int kt = 0; kt < nk; ++kt){
    bf16x8 a0 = *(const bf16x8*)(a0p + kt*32);
    bf16x8 a1 = *(const bf16x8*)(a1p + kt*32);
    #pragma unroll
    for (int j = 0; j < 4; ++j){
      bf16x8 bj = *(const bf16x8*)(bp0 + (size_t)(j*16)*K + kt*32);
      acc[0][j] = __builtin_amdgcn_mfma_f32_16x16x32_bf16(a0, bj, acc[0][j], 0, 0, 0);
      acc[1][j] = __builtin_amdgcn_mfma_f32_16x16x32_bf16(a1, bj, acc[1][j], 0, 0, 0);
    }
  }
  #pragma unroll
  for (int i = 0; i < 2; ++i){
    #pragma unroll
    for (int j = 0; j < 4; ++j){
      int rbase = blockIdx.x*64 + wr*32 + i*16 + (lane>>4)*4;
      int col   = colb + j*16 + (lane & 15);
      #pragma unroll
      for (int r = 0; r < 4; ++r){
        size_t o = (size_t)(rbase + r)*N + col;
        float v = acc[i][j][r];
        if (EPI == 1) outh[o] = f2bf(fmaxf(v, 0.f));
        else if (EPI == 2) outf[o] = add[o] + v;
      }
    }
  }
}

// ---------------- decomp v2 (UNCHANGED r22-pass) ----------------
template<int WHICH>
__global__ __launch_bounds__(256) void decomp_kernel(const float* __restrict__ in,
                                                     float* __restrict__ outf,
                                                     ushort* __restrict__ outh){
  int t = threadIdx.x;
  int gl = blockIdx.x*4 + (t >> 6);
  int c4 = (t & 63)*4;
  int b = gl >> 11, l = gl & (L_-1);
  const float* base = in + ((size_t)b*L_)*D_ + c4;
  float4 s = {0.f,0.f,0.f,0.f};
  float4 ctr;
  #pragma unroll
  for (int o = -3; o <= 3; ++o){
    int ll = (l + o + L_) & (L_-1);
    float4 v = *(const float4*)(base + (size_t)ll*D_);
    if (o == 0) ctr = v;
    s.x += v.x; s.y += v.y; s.z += v.z; s.w += v.w;
  }
  const float r7 = 1.f/7.f;
  float4 vv;
  vv.x = ctr.x - s.x*r7;
  vv.y = ctr.y - s.y*r7;
  vv.z = ctr.z - s.z*r7;
  vv.w = ctr.w - s.w*r7;
  size_t o0 = (size_t)gl*D_ + c4;
  if (WHICH == 0){
    *(float4*)(outf + o0) = vv;
    uint2 u = {cvt_pk_bf16(vv.x, vv.y), cvt_pk_bf16(vv.z, vv.w)};
    *(uint2*)(outh + o0) = u;
  } else {
    *(float4*)(outf + o0) = vv;
  }
}

__global__ void ws_diag_kernel(float* res0, float encoded){
  if (threadIdx.x == 0 && blockIdx.x == 0) res0[0] = encoded;
}

extern "C" void kernel_launch(void* const* d_in, const int* in_sizes, int n_in,
                              void* d_out, int out_size, void* d_ws, size_t ws_size,
                              hipStream_t stream) {
  const float* x  = (const float*)d_in[0];
  const float* Wq = (const float*)d_in[1];
  const float* Wk = (const float*)d_in[2];
  const float* Wv = (const float*)d_in[3];
  const float* Wo = (const float*)d_in[4];
  const float* W1 = (const float*)d_in[5];
  const float* W2 = (const float*)d_in[6];

  float* out      = (float*)d_out;
  float* res_out  = out;
  float* attn_out = out + RES_ELEMS;

  const size_t MiB = 1024ull*1024ull;
  const size_t NEEDED = 36*MiB + (MiB + MiB/2);

  if (ws_size < NEEDED){
    float enc = 1048576.0f + 1024.0f * (float)(ws_size / MiB);
    ws_diag_kernel<<<1, 64, 0, stream>>>(res_out, enc);
    return;
  }

  char* ws = (char*)d_ws;
  ushort* xb  = (ushort*)(ws + 0);
  ushort* ob  = (ushort*)(ws + 0);
  ushort* xdb = (ushort*)(ws + 0);
  ushort* qb  = (ushort*)(ws + 4*MiB);
  ushort* kb  = (ushort*)(ws + 8*MiB);
  float*  x1f = (float*) (ws + 4*MiB);
  float*  sf  = (float*) (ws + 4*MiB);
  ushort* vtb = (ushort*)(ws + 12*MiB);
  float*  xdf = (float*) (ws + 12*MiB);
  ushort* hb  = (ushort*)(ws + 20*MiB);
  ushort* wqt = (ushort*)(ws + 36*MiB);
  ushort* wkt = (ushort*)(ws + 36*MiB + 128*1024);
  ushort* wvt = (ushort*)(ws + 36*MiB + 256*1024);
  ushort* wot = (ushort*)(ws + 36*MiB + 384*1024);
  ushort* w1b = (ushort*)(ws + 36*MiB + 512*1024);
  ushort* w2b = (ushort*)(ws + 36*MiB + 1024*1024);

  // 1. prep
  {
    int total = (BL_*D_)/4 + 4*D_*D_ + 2*DFF_*D_;
    prep_kernel<<<(total+255)/256, 256, 0, stream>>>(x, Wq, Wk, Wv, Wo, W1, W2,
                                                     xb, wqt, wkt, wvt, wot, w1b, w2b);
  }
  // 2. QKV projections (64x128 template, Q pre-scaled)
  qkv_gemm<<<dim3(BL_/64, D_/128, 3), 256, 0, stream>>>(xb, wqt, wkt, wvt, qb, kb, vtb);
  // 3. attention v10 + setprio
  attn_kernel<<<dim3(B_*H_, L_/16), 256, 0, stream>>>(qb, kb, vtb, attn_out, ob);
  // 4. O projection + residual (64x128 template)
  gemm_bt<2><<<dim3(BL_/64, D_/128), 256, 0, stream>>>(ob, wot, BL_, D_, D_, x, x1f, nullptr);
  // 5. decomp1
  decomp_kernel<0><<<BL_/4, 256, 0, stream>>>(x1f, xdf, xdb);
  // 6. FFN1 (64x128 template)
  gemm_bt<1><<<dim3(BL_/64, DFF_/128), 256, 0, stream>>>(xdb, w1b, BL_, DFF_, D_, nullptr, nullptr, hb);
  // 7. FFN2 + residual (64x128 template)
  gemm_bt<2><<<dim3(BL_/64, D_/128), 256, 0, stream>>>(hb, w2b, BL_, D_, DFF_, xdf, sf, nullptr);
  // 8. decomp2 -> fp32 res
  decomp_kernel<1><<<BL_/4, 256, 0, stream>>>(sf, res_out, nullptr);
}

// Round 25
// 254.241 us; speedup vs baseline: 2.2541x; 1.0310x over previous
//
#include <hip/hip_runtime.h>
#include <hip/hip_bf16.h>

typedef __attribute__((ext_vector_type(8))) short bf16x8;
typedef __attribute__((ext_vector_type(4))) float f32x4;

#define B_    4
#define L_    2048
#define D_    256
#define H_    8
#define DH_   32
#define DFF_  1024
#define BL_   (B_*L_)          // 8192
#define RES_ELEMS (BL_*D_)     // 2097152
#define EFP   2056             // padded Ef row stride (bf16 elems)

__device__ __forceinline__ float bf2f(ushort u){
  union { unsigned int i; float f; } v; v.i = ((unsigned int)u)<<16; return v.f;
}
__device__ __forceinline__ ushort f2bf(float f){
  union { float f; unsigned int i; } v; v.f = f;
  unsigned int u = v.i;
  u += 0x7fffu + ((u>>16)&1u);   // round-to-nearest-even
  return (ushort)(u>>16);
}
__device__ __forceinline__ unsigned cvt_pk_bf16(float a, float b){
  unsigned r;
  asm("v_cvt_pk_bf16_f32 %0, %1, %2" : "=v"(r) : "v"(a), "v"(b));
  return r;
}
__device__ __forceinline__ float fast_exp2(float x){
  float r;
  asm("v_exp_f32 %0, %1" : "=v"(r) : "v"(x));
  return r;
}

// ---------------- prep v2 (UNCHANGED r24-pass) ----------------
__global__ void prep_kernel(const float* x, const float* Wq, const float* Wk, const float* Wv,
                            const float* Wo, const float* W1, const float* W2,
                            ushort* xb, ushort* wqt, ushort* wkt, ushort* wvt, ushort* wot,
                            ushort* w1b, ushort* w2b){
  int i = blockIdx.x*256 + threadIdx.x;
  const int NX4 = (BL_*D_) >> 2;       // 524288
  const int NW = D_*D_;
  const int NF = DFF_*D_;
  if (i < NX4){
    float4 v = *(const float4*)(x + (size_t)i*4);
    uint2 u = {cvt_pk_bf16(v.x, v.y), cvt_pk_bf16(v.z, v.w)};
    *(uint2*)(xb + (size_t)i*4) = u;
    return;
  }
  i -= NX4;
  if (i < NW) { int c = i>>8, k = i&255; wqt[i] = f2bf(Wq[k*D_+c]); return; }
  i -= NW;
  if (i < NW) { int c = i>>8, k = i&255; wkt[i] = f2bf(Wk[k*D_+c]); return; }
  i -= NW;
  if (i < NW) { int c = i>>8, k = i&255; wvt[i] = f2bf(Wv[k*D_+c]); return; }
  i -= NW;
  if (i < NW) { int c = i>>8, k = i&255; wot[i] = f2bf(Wo[k*D_+c]); return; }
  i -= NW;
  if (i < NF) { w1b[i] = f2bf(W1[i]); return; }
  i -= NF;
  if (i < NF) { w2b[i] = f2bf(W2[i]); return; }
}

// ---------------- qkv GEMM v4: 128x128 block, 64x64/wave (4A x 4B = 16 MFMA / 8 loads) ----------------
// grid (BL_/128, D_/128, 3) = (64, 2, 3) = 384 blocks.
__global__ __launch_bounds__(256) void qkv_gemm(const ushort* __restrict__ xb,
                         const ushort* __restrict__ wqt, const ushort* __restrict__ wkt,
                         const ushort* __restrict__ wvt,
                         ushort* __restrict__ qb, ushort* __restrict__ kb, ushort* __restrict__ vtb){
  int lane = threadIdx.x & 63, w = threadIdx.x >> 6;
  int rt = blockIdx.x, cg = blockIdx.y, mat = blockIdx.z;
  const ushort* Bt = (mat==0) ? wqt : (mat==1) ? wkt : wvt;
  int wr = w & 1, wc = w >> 1;
  int rowb = rt*128 + wr*64;
  int colb = cg*128 + wc*64;
  int kseg = lane >> 4;
  f32x4 acc[4][4] = {};
  const ushort* ap = xb + (size_t)(rowb + (lane & 15))*D_ + kseg*8;
  const ushort* bp = Bt + (size_t)(colb + (lane & 15))*D_ + kseg*8;
  #pragma unroll
  for (int kt = 0; kt < 8; ++kt){
    bf16x8 a[4], bb[4];
    #pragma unroll
    for (int i = 0; i < 4; ++i) a[i]  = *(const bf16x8*)(ap + (size_t)(i*16)*D_ + kt*32);
    #pragma unroll
    for (int j = 0; j < 4; ++j) bb[j] = *(const bf16x8*)(bp + (size_t)(j*16)*D_ + kt*32);
    #pragma unroll
    for (int i = 0; i < 4; ++i)
      #pragma unroll
      for (int j = 0; j < 4; ++j)
        acc[i][j] = __builtin_amdgcn_mfma_f32_16x16x32_bf16(a[i], bb[j], acc[i][j], 0, 0, 0);
  }
  const float SCL2E = 0.17677669529663687f * 1.4426950408889634f;
  float scl = (mat==0) ? SCL2E : 1.0f;
  #pragma unroll
  for (int i = 0; i < 4; ++i){
    #pragma unroll
    for (int j = 0; j < 4; ++j){
      int rbase = rowb + i*16 + (lane>>4)*4;
      int col   = colb + j*16 + (lane & 15);
      if (mat < 2){
        ushort* out = (mat==0) ? qb : kb;
        #pragma unroll
        for (int r = 0; r < 4; ++r) out[(size_t)(rbase+r)*D_ + col] = f2bf(acc[i][j][r]*scl);
      } else {
        int b = rbase >> 11, l = rbase & (L_-1);
        int h = col >> 5, d = col & 31;
        ushort* p = vtb + ((size_t)((b*H_ + h)*DH_ + d))*L_ + l;
        #pragma unroll
        for (int r = 0; r < 4; ++r) p[r] = f2bf(acc[i][j][r]);
      }
    }
  }
}

// ---------------- attention v10 + setprio (UNCHANGED r24-pass) ----------------
__global__ __launch_bounds__(256) void attn_kernel(const ushort* __restrict__ qb,
                          const ushort* __restrict__ kb, const ushort* __restrict__ vtb,
                          float* __restrict__ attn_out, ushort* __restrict__ ob){
  __shared__ ushort Ef[16][EFP];        // packed bf16 E (64.3 KB)
  __shared__ float part[4*16*32];
  __shared__ float red[4][16];
  __shared__ float rrowInv[16];
  int tid = threadIdx.x, lane = tid & 63, w = tid >> 6;
  int bh = blockIdx.x, rt = blockIdx.y;    // bh fastest -> XCD = bh%8
  int b = bh >> 3, h = bh & 7;
  int l0 = rt*16;
  int ql = lane & 15, g = lane >> 4;

  bf16x8 qfrag = *(const bf16x8*)(qb + (size_t)(b*L_ + l0 + ql)*D_ + h*DH_ + g*8);
  const ushort* kbase = kb + (size_t)(b)*L_*D_ + h*DH_ + g*8;

  float ssum = 0.f;
  f32x4 acc0 = {0.f,0.f,0.f,0.f}, acc1 = {0.f,0.f,0.f,0.f};
  const ushort* v0p = vtb + ((size_t)(bh*DH_) + ql)*L_;
  const ushort* v1p = vtb + ((size_t)(bh*DH_) + 16 + ql)*L_;

  __builtin_amdgcn_s_setprio(1);
  for (int jj = 0; jj < 4; ++jj){
    bf16x8 kf[8];
    bf16x8 vf0[4], vf1[4];
    #pragma unroll
    for (int p = 0; p < 8; ++p){
      int ct = w*32 + jj*8 + p;
      kf[p] = *(const bf16x8*)(kbase + (size_t)(ct*16 + ql)*D_);
    }
    #pragma unroll
    for (int q = 0; q < 4; ++q){
      int kt = w*16 + jj*4 + q;
      vf0[q] = *(const bf16x8*)(v0p + kt*32 + g*8);
      vf1[q] = *(const bf16x8*)(v1p + kt*32 + g*8);
    }
    #pragma unroll
    for (int p = 0; p < 8; ++p){
      int ct = w*32 + jj*8 + p;
      f32x4 acc = {0.f,0.f,0.f,0.f};
      acc = __builtin_amdgcn_mfma_f32_16x16x32_bf16(kf[p], qfrag, acc, 0, 0, 0);
      float e0 = fast_exp2(acc[0]);
      float e1 = fast_exp2(acc[1]);
      float e2 = fast_exp2(acc[2]);
      float e3 = fast_exp2(acc[3]);
      ssum += (e0 + e1) + (e2 + e3);
      uint2 u = {cvt_pk_bf16(e0, e1), cvt_pk_bf16(e2, e3)};
      *(uint2*)(&Ef[ql][ct*16 + g*4]) = u;
    }
    #pragma unroll
    for (int q = 0; q < 4; ++q){
      int kt = w*16 + jj*4 + q;
      bf16x8 pf = *(const bf16x8*)(&Ef[ql][kt*32 + g*8]);
      acc0 = __builtin_amdgcn_mfma_f32_16x16x32_bf16(pf, vf0[q], acc0, 0, 0, 0);
      acc1 = __builtin_amdgcn_mfma_f32_16x16x32_bf16(pf, vf1[q], acc1, 0, 0, 0);
    }
  }
  __builtin_amdgcn_s_setprio(0);

  ssum += __shfl_xor(ssum, 16);
  ssum += __shfl_xor(ssum, 32);
  if (lane < 16) red[w][ql] = ssum;
  {
    int rb = g*4;
    #pragma unroll
    for (int r = 0; r < 4; ++r){
      part[(w*16 + rb + r)*32 + ql]      = acc0[r];
      part[(w*16 + rb + r)*32 + 16 + ql] = acc1[r];
    }
  }
  __syncthreads();
  if (tid < 16)
    rrowInv[tid] = 1.f / (red[0][tid] + red[1][tid] + red[2][tid] + red[3][tid]);
  __syncthreads();

  float* obase = attn_out + ((size_t)bh*L_ + l0)*L_;
  #pragma unroll
  for (int r = 0; r < 16; ++r){
    float rv = rrowInv[r];
    float* orow = obase + (size_t)r*L_;
    #pragma unroll
    for (int rd = 0; rd < 2; ++rd){
      int off = rd*1024 + tid*4;
      uint2 u = *(const uint2*)(&Ef[r][off]);
      float4 st;
      st.x = __uint_as_float(u.x << 16) * rv;
      st.y = __uint_as_float(u.x & 0xffff0000u) * rv;
      st.z = __uint_as_float(u.y << 16) * rv;
      st.w = __uint_as_float(u.y & 0xffff0000u) * rv;
      *(float4*)(orow + off) = st;
    }
  }

  for (int idx = tid; idx < 512; idx += 256){
    int row = idx >> 5, d = idx & 31;
    float sum = (part[(0*16+row)*32 + d] + part[(1*16+row)*32 + d]
               + part[(2*16+row)*32 + d] + part[(3*16+row)*32 + d]) * rrowInv[row];
    ob[(size_t)(b*L_ + l0 + row)*D_ + h*DH_ + d] = f2bf(sum);
  }
}

// ---------------- generic GEMM v3 (64x128, UNCHANGED r24) — for N=256 shapes ----------------
template<int EPI>
__global__ __launch_bounds__(256) void gemm_bt(const ushort* __restrict__ A, const ushort* __restrict__ Bt,
                        int M, int N, int K,
                        const float* __restrict__ add, float* __restrict__ outf,
                        ushort* __restrict__ outh){
  int lane = threadIdx.x & 63, w = threadIdx.x >> 6;
  int wr = w & 1, wc = w >> 1;
  int row0 = blockIdx.x*64 + wr*32 + (lane & 15);
  int colb = blockIdx.y*128 + wc*64;
  int kseg = lane >> 4;
  f32x4 acc[2][4] = {};
  const ushort* a0p = A + (size_t)row0*K + kseg*8;
  const ushort* a1p = a0p + (size_t)16*K;
  const ushort* bp0 = Bt + (size_t)(colb + (lane & 15))*K + kseg*8;
  int nk = K >> 5;
  #pragma unroll 4
  for (int kt = 0; kt < nk; ++kt){
    bf16x8 a0 = *(const bf16x8*)(a0p + kt*32);
    bf16x8 a1 = *(const bf16x8*)(a1p + kt*32);
    #pragma unroll
    for (int j = 0; j < 4; ++j){
      bf16x8 bj = *(const bf16x8*)(bp0 + (size_t)(j*16)*K + kt*32);
      acc[0][j] = __builtin_amdgcn_mfma_f32_16x16x32_bf16(a0, bj, acc[0][j], 0, 0, 0);
      acc[1][j] = __builtin_amdgcn_mfma_f32_16x16x32_bf16(a1, bj, acc[1][j], 0, 0, 0);
    }
  }
  #pragma unroll
  for (int i = 0; i < 2; ++i){
    #pragma unroll
    for (int j = 0; j < 4; ++j){
      int rbase = blockIdx.x*64 + wr*32 + i*16 + (lane>>4)*4;
      int col   = colb + j*16 + (lane & 15);
      #pragma unroll
      for (int r = 0; r < 4; ++r){
        size_t o = (size_t)(rbase + r)*N + col;
        float v = acc[i][j][r];
        if (EPI == 1) outh[o] = f2bf(fmaxf(v, 0.f));
        else if (EPI == 2) outf[o] = add[o] + v;
      }
    }
  }
}

// ---------------- big GEMM: 128x128 block, 64x64/wave (16 MFMA / 8 loads) — for FFN1 ----------------
template<int EPI>
__global__ __launch_bounds__(256) void gemm_big(const ushort* __restrict__ A, const ushort* __restrict__ Bt,
                        int M, int N, int K,
                        const float* __restrict__ add, float* __restrict__ outf,
                        ushort* __restrict__ outh){
  int lane = threadIdx.x & 63, w = threadIdx.x >> 6;
  int wr = w & 1, wc = w >> 1;
  int rowb = blockIdx.x*128 + wr*64;
  int colb = blockIdx.y*128 + wc*64;
  int kseg = lane >> 4;
  f32x4 acc[4][4] = {};
  const ushort* ap = A + (size_t)(rowb + (lane & 15))*K + kseg*8;
  const ushort* bp = Bt + (size_t)(colb + (lane & 15))*K + kseg*8;
  int nk = K >> 5;
  #pragma unroll 2
  for (int kt = 0; kt < nk; ++kt){
    bf16x8 a[4], bb[4];
    #pragma unroll
    for (int i = 0; i < 4; ++i) a[i]  = *(const bf16x8*)(ap + (size_t)(i*16)*K + kt*32);
    #pragma unroll
    for (int j = 0; j < 4; ++j) bb[j] = *(const bf16x8*)(bp + (size_t)(j*16)*K + kt*32);
    #pragma unroll
    for (int i = 0; i < 4; ++i)
      #pragma unroll
      for (int j = 0; j < 4; ++j)
        acc[i][j] = __builtin_amdgcn_mfma_f32_16x16x32_bf16(a[i], bb[j], acc[i][j], 0, 0, 0);
  }
  #pragma unroll
  for (int i = 0; i < 4; ++i){
    #pragma unroll
    for (int j = 0; j < 4; ++j){
      int rbase = rowb + i*16 + (lane>>4)*4;
      int col   = colb + j*16 + (lane & 15);
      #pragma unroll
      for (int r = 0; r < 4; ++r){
        size_t o = (size_t)(rbase + r)*N + col;
        float v = acc[i][j][r];
        if (EPI == 1) outh[o] = f2bf(fmaxf(v, 0.f));
        else if (EPI == 2) outf[o] = add[o] + v;
      }
    }
  }
}

// ---------------- decomp v2 (UNCHANGED r24-pass) ----------------
template<int WHICH>
__global__ __launch_bounds__(256) void decomp_kernel(const float* __restrict__ in,
                                                     float* __restrict__ outf,
                                                     ushort* __restrict__ outh){
  int t = threadIdx.x;
  int gl = blockIdx.x*4 + (t >> 6);
  int c4 = (t & 63)*4;
  int b = gl >> 11, l = gl & (L_-1);
  const float* base = in + ((size_t)b*L_)*D_ + c4;
  float4 s = {0.f,0.f,0.f,0.f};
  float4 ctr;
  #pragma unroll
  for (int o = -3; o <= 3; ++o){
    int ll = (l + o + L_) & (L_-1);
    float4 v = *(const float4*)(base + (size_t)ll*D_);
    if (o == 0) ctr = v;
    s.x += v.x; s.y += v.y; s.z += v.z; s.w += v.w;
  }
  const float r7 = 1.f/7.f;
  float4 vv;
  vv.x = ctr.x - s.x*r7;
  vv.y = ctr.y - s.y*r7;
  vv.z = ctr.z - s.z*r7;
  vv.w = ctr.w - s.w*r7;
  size_t o0 = (size_t)gl*D_ + c4;
  if (WHICH == 0){
    *(float4*)(outf + o0) = vv;
    uint2 u = {cvt_pk_bf16(vv.x, vv.y), cvt_pk_bf16(vv.z, vv.w)};
    *(uint2*)(outh + o0) = u;
  } else {
    *(float4*)(outf + o0) = vv;
  }
}

__global__ void ws_diag_kernel(float* res0, float encoded){
  if (threadIdx.x == 0 && blockIdx.x == 0) res0[0] = encoded;
}

extern "C" void kernel_launch(void* const* d_in, const int* in_sizes, int n_in,
                              void* d_out, int out_size, void* d_ws, size_t ws_size,
                              hipStream_t stream) {
  const float* x  = (const float*)d_in[0];
  const float* Wq = (const float*)d_in[1];
  const float* Wk = (const float*)d_in[2];
  const float* Wv = (const float*)d_in[3];
  const float* Wo = (const float*)d_in[4];
  const float* W1 = (const float*)d_in[5];
  const float* W2 = (const float*)d_in[6];

  float* out      = (float*)d_out;
  float* res_out  = out;
  float* attn_out = out + RES_ELEMS;

  const size_t MiB = 1024ull*1024ull;
  const size_t NEEDED = 36*MiB + (MiB + MiB/2);

  if (ws_size < NEEDED){
    float enc = 1048576.0f + 1024.0f * (float)(ws_size / MiB);
    ws_diag_kernel<<<1, 64, 0, stream>>>(res_out, enc);
    return;
  }

  char* ws = (char*)d_ws;
  ushort* xb  = (ushort*)(ws + 0);
  ushort* ob  = (ushort*)(ws + 0);
  ushort* xdb = (ushort*)(ws + 0);
  ushort* qb  = (ushort*)(ws + 4*MiB);
  ushort* kb  = (ushort*)(ws + 8*MiB);
  float*  x1f = (float*) (ws + 4*MiB);
  float*  sf  = (float*) (ws + 4*MiB);
  ushort* vtb = (ushort*)(ws + 12*MiB);
  float*  xdf = (float*) (ws + 12*MiB);
  ushort* hb  = (ushort*)(ws + 20*MiB);
  ushort* wqt = (ushort*)(ws + 36*MiB);
  ushort* wkt = (ushort*)(ws + 36*MiB + 128*1024);
  ushort* wvt = (ushort*)(ws + 36*MiB + 256*1024);
  ushort* wot = (ushort*)(ws + 36*MiB + 384*1024);
  ushort* w1b = (ushort*)(ws + 36*MiB + 512*1024);
  ushort* w2b = (ushort*)(ws + 36*MiB + 1024*1024);

  // 1. prep
  {
    int total = (BL_*D_)/4 + 4*D_*D_ + 2*DFF_*D_;
    prep_kernel<<<(total+255)/256, 256, 0, stream>>>(x, Wq, Wk, Wv, Wo, W1, W2,
                                                     xb, wqt, wkt, wvt, wot, w1b, w2b);
  }
  // 2. QKV projections (128x128 template, Q pre-scaled)
  qkv_gemm<<<dim3(BL_/128, D_/128, 3), 256, 0, stream>>>(xb, wqt, wkt, wvt, qb, kb, vtb);
  // 3. attention v10 + setprio
  attn_kernel<<<dim3(B_*H_, L_/16), 256, 0, stream>>>(qb, kb, vtb, attn_out, ob);
  // 4. O projection + residual (64x128; N=256 keeps 256 blocks)
  gemm_bt<2><<<dim3(BL_/64, D_/128), 256, 0, stream>>>(ob, wot, BL_, D_, D_, x, x1f, nullptr);
  // 5. decomp1
  decomp_kernel<0><<<BL_/4, 256, 0, stream>>>(x1f, xdf, xdb);
  // 6. FFN1 (128x128 big template; 512 blocks)
  gemm_big<1><<<dim3(BL_/128, DFF_/128), 256, 0, stream>>>(xdb, w1b, BL_, DFF_, D_, nullptr, nullptr, hb);
  // 7. FFN2 + residual (64x128)
  gemm_bt<2><<<dim3(BL_/64, D_/128), 256, 0, stream>>>(hb, w2b, BL_, D_, DFF_, xdf, sf, nullptr);
  // 8. decomp2 -> fp32 res
  decomp_kernel<1><<<BL_/4, 256, 0, stream>>>(sf, res_out, nullptr);
}